// Round 11
// baseline (285.548 us; speedup 1.0000x reference)
//
#include <hip/hip_runtime.h>

// LovaszSoftmaxLoss B=8, C=21, H=W=512 — sort-free counting-sort formulation.
// loss = sum_i e_i*(g_i - g_{i-1}) over descending-sorted errors; equal-key
// runs contribute e*(g(b)-g(a-1)) independent of tie order, so a histogram
// over quantized keys suffices. Key = 12 octaves x 6 mantissa bits = 768 bins.
//
// R13 post-mortem: occupancy 41->~100%, barriers 21->0, prefetch added: total
// UNCHANGED (282 vs 284/287). Everything varied across R4-R13 EXCEPT the 44M
// LDS atomicAdds (1 per pixel-class, hot-binned). Implied ~60 cyc/wave-atomic
// == intra-instruction SAME-ADDRESS serialization (e=p concentrates in ~100
// bins; same-address RMWs retire serially; bank-conflict counter stays low
// because that's not a bank conflict). Never ablated until now.
// R14 (infra-failed, resubmitted as R15): SINGLE change vs R13 — 2x hist
// replicas split by lane>>5 (126 KB LDS hist, 138 KB total, 1 block/CU,
// 16 waves — R10 proved 16w==32w here). Halves same-address multiplicity
// per wave-atomic at zero VALU cost. Flush folds replicas (packed add
// exact: count<=4096<2^13, labelsum<=81920<2^18).
// Predict: if atomics are the wall, k_fused ~95 -> 55-75us, total ~245-260;
// if unchanged (+-10), atomics exonerated -> pivot to the read path.

#define NB     8
#define NC     21
#define NPIX   262144
#define NROWS  (NB * NC)       // 168
#define NBINS  768             // key = (fexp+12)<<6 | mant6 ; fexp in [-12,0]
#define CHUNKS 64              // blocks per batch
#define CHUNK  (NPIX / CHUNKS) // 4096 pixels per block
#define HSZ    (NC * NBINS)    // 16128
#define LOG2E  1.4426950408889634f

// ---------------- Fused kernel ----------------
// 512 blocks x 1024 threads. LDS bin u32 = count<<18 | labelsum
// (count<=4096 -> <<18 caps 2^30, labelsum<=81920 < 2^18).
__global__ __launch_bounds__(1024, 4) void k_fused(
    const float* __restrict__ x,
    const int* __restrict__ tgt,
    unsigned* __restrict__ partial) {
  __shared__ unsigned      hist[2 * HSZ];     // 126 KB (2 replicas by lane>>5)
  __shared__ _Float16      Ls[CHUNK];         // 8 KB  (L2 = log2 Z per px)
  __shared__ unsigned char labs[CHUNK];       // 4 KB

  int tid   = threadIdx.x;
  int b     = blockIdx.x >> 6;
  int chunk = blockIdx.x & 63;
  const float* xb = x + (size_t)b * NC * NPIX + (size_t)chunk * CHUNK;

  for (int i = tid; i < 2 * HSZ; i += 1024) hist[i] = 0;

  // ---- phase 1: Z over 21 classes for this thread's 4 px; stash L2 + labels ----
  // no max-sub: N(0,1) logits bounded, exp2 safe in f32.
  int n4 = tid * 4;
  float Z0 = 0.f, Z1 = 0.f, Z2 = 0.f, Z3 = 0.f;
  #pragma unroll
  for (int c = 0; c < NC; ++c) {
    float4 t = *(const float4*)(xb + (size_t)c * NPIX + n4);
    Z0 += exp2f(t.x * LOG2E);
    Z1 += exp2f(t.y * LOG2E);
    Z2 += exp2f(t.z * LOG2E);
    Z3 += exp2f(t.w * LOG2E);
  }
  Ls[n4 + 0] = (_Float16)__log2f(Z0);
  Ls[n4 + 1] = (_Float16)__log2f(Z1);
  Ls[n4 + 2] = (_Float16)__log2f(Z2);
  Ls[n4 + 3] = (_Float16)__log2f(Z3);
  {
    int4 tv = *(const int4*)(tgt + (size_t)b * NPIX + (size_t)chunk * CHUNK + n4);
    *(unsigned*)(labs + n4) = (unsigned)tv.x | ((unsigned)tv.y << 8) |
                              ((unsigned)tv.z << 16) | ((unsigned)tv.w << 24);
  }
  __syncthreads();   // hist zeroed + Ls/labs staged

  // ---- phase 2: 42 items = (class, half); wave-owned hists; NO barriers ----
  int wave = tid >> 6, lane = tid & 63;
  unsigned* hrep = hist + (lane >> 5) * HSZ;   // replica by lane half
  struct H4 { _Float16 v[4]; };
  for (int ii = wave; ii < 2 * NC; ii += 16) {
    int c = ii >> 1, h = ii & 1;
    const float* xc = xb + (size_t)c * NPIX + h * 2048;
    unsigned* hc = hrep + c * NBINS;

    float4 nxt = *(const float4*)(xc + lane * 4);
    #pragma unroll
    for (int it = 0; it < 8; ++it) {
      float4 cur = nxt;
      if (it < 7) nxt = *(const float4*)(xc + (it + 1) * 256 + lane * 4);
      int px = h * 2048 + it * 256 + lane * 4;
      H4 l4 = *(const H4*)(Ls + px);
      unsigned lb = *(const unsigned*)(labs + px);
      float xs[4] = {cur.x, cur.y, cur.z, cur.w};
      #pragma unroll
      for (int j = 0; j < 4; ++j) {
        float L2q = (float)l4.v[j];
        float p   = exp2f(fmaf(xs[j], LOG2E, -L2q));   // softmax prob
        unsigned lab = (lb >> (8 * j)) & 255u;
        float sel = ((int)lab == c) ? 1.0f : 0.0f;
        float e   = fabsf(sel - p);                    // e in [0,1]
        int k = (int)(__float_as_uint(e) >> 17) - 7360; // ((fexp+12)<<6)|mant6
        k = min(max(k, 0), NBINS - 1);                 // e<2^-12 -> 0; e>=1 -> top
        atomicAdd(hc + k, (1u << 18) | lab);
      }
    }
  }
  __syncthreads();

  // fold replicas and write partial (packed add exact; fields can't overflow)
  unsigned* op = partial + (size_t)blockIdx.x * HSZ;
  for (int i = tid; i < HSZ; i += 1024) op[i] = hist[i] + hist[HSZ + i];
}

// ---------------- u64 shuffle helpers ----------------
__device__ inline unsigned long long shfl_up_u64(unsigned long long v, int off) {
  unsigned lo = (unsigned)v, hi = (unsigned)(v >> 32);
  lo = (unsigned)__shfl_up((int)lo, off, 64);
  hi = (unsigned)__shfl_up((int)hi, off, 64);
  return ((unsigned long long)hi << 32) | lo;
}
__device__ inline unsigned long long shfl_down_u64(unsigned long long v, int off) {
  unsigned lo = (unsigned)v, hi = (unsigned)(v >> 32);
  lo = (unsigned)__shfl_down((int)lo, off, 64);
  hi = (unsigned)__shfl_down((int)hi, off, 64);
  return ((unsigned long long)hi << 32) | lo;
}

// ---------------- Scan kernel: merge 64 partials/row + descending scan ----------------
// 168 blocks x 768 threads (12 waves); one thread per bin. (Verified R11/R13.)
__global__ __launch_bounds__(768) void k_scan(
    const unsigned* __restrict__ partial,
    float* __restrict__ out) {
  int row  = blockIdx.x;                     // 0..167
  int b    = row / NC;
  int c    = row - b * NC;
  int tid  = threadIdx.x;                    // == bin slot
  int lane = tid & 63;
  int wave = tid >> 6;                       // 12 waves

  __shared__ unsigned long long hist0[NBINS];   // 6 KB
  __shared__ unsigned long long wtot[12];
  __shared__ double wred[12];
  __shared__ double sT;

  // merge 64 block-partials for (b, c): coalesced 768-wide loads
  {
    const unsigned* pp = partial + ((size_t)(b * CHUNKS) * NC + c) * NBINS + tid;
    unsigned long long cnt = 0, ls = 0;
    #pragma unroll 8
    for (int j = 0; j < CHUNKS; ++j) {
      unsigned v = pp[(size_t)j * NC * NBINS];
      cnt += (v >> 18);
      ls  += (v & 0x3FFFFu);
    }
    hist0[tid] = (cnt << 32) | ls;
  }
  __syncthreads();

  // total labelsum T (exact; fields can't overflow: cnt<=262144, ls<=5.3M)
  unsigned long long tot = hist0[tid];
  #pragma unroll
  for (int off = 32; off > 0; off >>= 1) tot += shfl_down_u64(tot, off);
  if (lane == 0) wtot[wave] = tot;
  __syncthreads();
  if (tid == 0) {
    unsigned long long g = 0;
    #pragma unroll
    for (int w = 0; w < 12; ++w) g += wtot[w];
    sT = (double)(unsigned)(g & 0xffffffffULL);
  }
  __syncthreads();
  double T = sT;
  __syncthreads();

  // single-chunk descending scan over 768 bins
  int bin = (NBINS - 1) - tid;
  unsigned long long v = hist0[bin];

  unsigned long long s = v;                  // intra-wave inclusive scan
  #pragma unroll
  for (int off = 1; off < 64; off <<= 1) {
    unsigned long long u = shfl_up_u64(s, off);
    if (lane >= off) s += u;
  }
  if (lane == 63) wtot[wave] = s;
  __syncthreads();

  unsigned long long woff = 0;
  for (int w = 0; w < wave; ++w) woff += wtot[w];
  unsigned long long excl = s - v + woff;    // strictly-greater prefix

  double acc = 0.0;
  unsigned n = (unsigned)(v >> 32);
  if (n) {
    unsigned sl = (unsigned)(v & 0xffffffffu);
    unsigned cb = (unsigned)(excl >> 32);
    unsigned sb = (unsigned)(excl & 0xffffffffu);
    double Sb = (double)sb + (double)sl;
    double gb = 1.0 - (T - Sb) / (T + (double)(cb + n) - Sb);
    double ga = (cb == 0) ? 0.0
                          : 1.0 - (T - (double)sb) / (T + (double)cb - (double)sb);
    unsigned key = (unsigned)bin;
    unsigned ex  = key >> 6, mant = key & 63u;
    float e = ldexpf(1.0f + ((float)mant + 0.5f) * 0.015625f, (int)ex - 12);
    acc = (double)e * (gb - ga);
  }

  // block reduce acc (12 waves)
  #pragma unroll
  for (int off = 32; off > 0; off >>= 1) acc += __shfl_down(acc, off, 64);
  if (lane == 0) wred[wave] = acc;
  __syncthreads();
  if (tid == 0) {
    double ssum = 0.0;
    #pragma unroll
    for (int w = 0; w < 12; ++w) ssum += wred[w];
    atomicAdd(out, (float)(ssum * (1.0 / (double)NROWS)));
  }
}

extern "C" void kernel_launch(void* const* d_in, const int* in_sizes, int n_in,
                              void* d_out, int out_size, void* d_ws, size_t ws_size,
                              hipStream_t stream) {
  const float* x  = (const float*)d_in[0];   // (B, C, H, W) float32
  const int* tgt  = (const int*)d_in[1];     // (B, H, W) int32
  float* out      = (float*)d_out;
  unsigned* partial = (unsigned*)d_ws;       // 512*21*768*4 = 33 MB

  hipMemsetAsync(d_out, 0, sizeof(float), stream);
  k_fused<<<NB * CHUNKS, 1024, 0, stream>>>(x, tgt, partial);
  k_scan<<<NROWS, NBINS, 0, stream>>>(partial, out);
}

// Round 12
// 282.975 us; speedup vs baseline: 1.0091x; 1.0091x over previous
//
#include <hip/hip_runtime.h>

// LovaszSoftmaxLoss B=8, C=21, H=W=512 — sort-free counting-sort formulation.
// loss = sum_i e_i*(g_i - g_{i-1}) over descending-sorted errors; equal-key
// runs contribute e*(g(b)-g(a-1)) independent of tie order, so a histogram
// over quantized keys suffices. R15 bins are LOG-UNIFORM: 64 bins/octave over
// 12 octaves (width 2^(1/64)=1.09%, center err +-0.55% — same budget as the
// old mantissa bins), key = floor(64*(log2(e)+12)).
//
// R14 post-mortem: replica split null -> same-address atomics exonerated.
// LLC-resident replay rows ran at the SAME 108us with FETCH~0 -> HBM BW
// exonerated too. Falsified: spills, traffic, occupancy, barriers, global
// atomics, addr-collision atomics, bank conflicts (5%). Largest remaining
// block: phase-2's per-pixel-class chain (~9 VALU + 1 trans + ds_add) x 44M
// — never reduced, only moved. R15 (single change vs R13): log-domain
// binning. Non-target classes: log2(p) = x*LOG2E - L2 needs NO exp ->
// k = clamp(floor(fma(x, 64LOG2E, kb))), 5 VALU + ds_add. Target lanes
// (~3/64) take exec-masked exp2+log2 path. k_scan: e = 2^((k+.5)/64 - 12).
// Predict: k_fused ~100 -> 75-85us, total 282.5 -> 255-270; unchanged ->
// phase-2 hidden, structure at floor -> declare next round.

#define NB     8
#define NC     21
#define NPIX   262144
#define NROWS  (NB * NC)       // 168
#define NBINS  768
#define CHUNKS 64              // blocks per batch
#define CHUNK  (NPIX / CHUNKS) // 4096 pixels per block
#define HSZ    (NC * NBINS)    // 16128
#define LOG2E    1.4426950408889634f
#define C64LOG2E 92.33248261689366f   // 64*log2(e)

// ---------------- Fused kernel ----------------
// 512 blocks x 1024 threads. LDS bin u32 = count<<18 | labelsum
// (count<=4096 -> <<18 caps 2^30, labelsum<=81920 < 2^18).
__global__ __launch_bounds__(1024, 8) void k_fused(
    const float* __restrict__ x,
    const int* __restrict__ tgt,
    unsigned* __restrict__ partial) {
  __shared__ unsigned      hist[HSZ];         // 63 KB
  __shared__ _Float16      Ls[CHUNK];         // 8 KB  (L2 = log2 Z per px)
  __shared__ unsigned char labs[CHUNK];       // 4 KB

  int tid   = threadIdx.x;
  int b     = blockIdx.x >> 6;
  int chunk = blockIdx.x & 63;
  const float* xb = x + (size_t)b * NC * NPIX + (size_t)chunk * CHUNK;

  for (int i = tid; i < HSZ; i += 1024) hist[i] = 0;

  // ---- phase 1: Z over 21 classes for this thread's 4 px; stash L2 + labels ----
  // no max-sub: N(0,1) logits bounded, exp2 safe in f32.
  int n4 = tid * 4;
  float Z0 = 0.f, Z1 = 0.f, Z2 = 0.f, Z3 = 0.f;
  #pragma unroll
  for (int c = 0; c < NC; ++c) {
    float4 t = *(const float4*)(xb + (size_t)c * NPIX + n4);
    Z0 += exp2f(t.x * LOG2E);
    Z1 += exp2f(t.y * LOG2E);
    Z2 += exp2f(t.z * LOG2E);
    Z3 += exp2f(t.w * LOG2E);
  }
  Ls[n4 + 0] = (_Float16)__log2f(Z0);
  Ls[n4 + 1] = (_Float16)__log2f(Z1);
  Ls[n4 + 2] = (_Float16)__log2f(Z2);
  Ls[n4 + 3] = (_Float16)__log2f(Z3);
  {
    int4 tv = *(const int4*)(tgt + (size_t)b * NPIX + (size_t)chunk * CHUNK + n4);
    *(unsigned*)(labs + n4) = (unsigned)tv.x | ((unsigned)tv.y << 8) |
                              ((unsigned)tv.z << 16) | ((unsigned)tv.w << 24);
  }
  __syncthreads();   // hist zeroed + Ls/labs staged

  // ---- phase 2: 42 items = (class, half); wave-owned hists; NO barriers ----
  int wave = tid >> 6, lane = tid & 63;
  struct H4 { _Float16 v[4]; };
  for (int ii = wave; ii < 2 * NC; ii += 16) {
    int c = ii >> 1, h = ii & 1;
    const float* xc = xb + (size_t)c * NPIX + h * 2048;
    unsigned* hc = hist + c * NBINS;

    float4 nxt = *(const float4*)(xc + lane * 4);
    #pragma unroll
    for (int it = 0; it < 8; ++it) {
      float4 cur = nxt;
      if (it < 7) nxt = *(const float4*)(xc + (it + 1) * 256 + lane * 4);
      int px = h * 2048 + it * 256 + lane * 4;
      H4 l4 = *(const H4*)(Ls + px);
      unsigned lb = *(const unsigned*)(labs + px);
      float xs[4] = {cur.x, cur.y, cur.z, cur.w};
      #pragma unroll
      for (int j = 0; j < 4; ++j) {
        float L2q = (float)l4.v[j];
        unsigned lab = (lb >> (8 * j)) & 255u;
        // y = 64*log2(p) + 768, with log2(p) = x*log2e - L2  (no exp needed)
        float y = fmaf(xs[j], C64LOG2E, fmaf(L2q, -64.0f, 768.0f));
        int k;
        if ((int)lab == c) {
          // target class: e = 1 - p (masked slow path, ~3/64 lanes)
          float p = exp2f((y - 768.0f) * 0.015625f);
          k = (int)floorf(fmaf(__log2f(1.0f - p), 64.0f, 768.0f));
        } else {
          k = (int)floorf(y);                // e = p
        }
        k = min(max(k, 0), NBINS - 1);       // e<2^-12 -> 0; e>=1 edge -> top
        atomicAdd(hc + k, (1u << 18) | lab);
      }
    }
  }
  __syncthreads();

  unsigned* op = partial + (size_t)blockIdx.x * HSZ;
  for (int i = tid; i < HSZ; i += 1024) op[i] = hist[i];
}

// ---------------- u64 shuffle helpers ----------------
__device__ inline unsigned long long shfl_up_u64(unsigned long long v, int off) {
  unsigned lo = (unsigned)v, hi = (unsigned)(v >> 32);
  lo = (unsigned)__shfl_up((int)lo, off, 64);
  hi = (unsigned)__shfl_up((int)hi, off, 64);
  return ((unsigned long long)hi << 32) | lo;
}
__device__ inline unsigned long long shfl_down_u64(unsigned long long v, int off) {
  unsigned lo = (unsigned)v, hi = (unsigned)(v >> 32);
  lo = (unsigned)__shfl_down((int)lo, off, 64);
  hi = (unsigned)__shfl_down((int)hi, off, 64);
  return ((unsigned long long)hi << 32) | lo;
}

// ---------------- Scan kernel: merge 64 partials/row + descending scan ----------------
// 168 blocks x 768 threads (12 waves); one thread per bin. (Verified R11/R13;
// only the e-reconstruction changes for log-uniform bins.)
__global__ __launch_bounds__(768) void k_scan(
    const unsigned* __restrict__ partial,
    float* __restrict__ out) {
  int row  = blockIdx.x;                     // 0..167
  int b    = row / NC;
  int c    = row - b * NC;
  int tid  = threadIdx.x;                    // == bin slot
  int lane = tid & 63;
  int wave = tid >> 6;                       // 12 waves

  __shared__ unsigned long long hist0[NBINS];   // 6 KB
  __shared__ unsigned long long wtot[12];
  __shared__ double wred[12];
  __shared__ double sT;

  // merge 64 block-partials for (b, c): coalesced 768-wide loads
  {
    const unsigned* pp = partial + ((size_t)(b * CHUNKS) * NC + c) * NBINS + tid;
    unsigned long long cnt = 0, ls = 0;
    #pragma unroll 8
    for (int j = 0; j < CHUNKS; ++j) {
      unsigned v = pp[(size_t)j * NC * NBINS];
      cnt += (v >> 18);
      ls  += (v & 0x3FFFFu);
    }
    hist0[tid] = (cnt << 32) | ls;
  }
  __syncthreads();

  // total labelsum T (exact; fields can't overflow: cnt<=262144, ls<=5.3M)
  unsigned long long tot = hist0[tid];
  #pragma unroll
  for (int off = 32; off > 0; off >>= 1) tot += shfl_down_u64(tot, off);
  if (lane == 0) wtot[wave] = tot;
  __syncthreads();
  if (tid == 0) {
    unsigned long long g = 0;
    #pragma unroll
    for (int w = 0; w < 12; ++w) g += wtot[w];
    sT = (double)(unsigned)(g & 0xffffffffULL);
  }
  __syncthreads();
  double T = sT;
  __syncthreads();

  // single-chunk descending scan over 768 bins
  int bin = (NBINS - 1) - tid;
  unsigned long long v = hist0[bin];

  unsigned long long s = v;                  // intra-wave inclusive scan
  #pragma unroll
  for (int off = 1; off < 64; off <<= 1) {
    unsigned long long u = shfl_up_u64(s, off);
    if (lane >= off) s += u;
  }
  if (lane == 63) wtot[wave] = s;
  __syncthreads();

  unsigned long long woff = 0;
  for (int w = 0; w < wave; ++w) woff += wtot[w];
  unsigned long long excl = s - v + woff;    // strictly-greater prefix

  double acc = 0.0;
  unsigned n = (unsigned)(v >> 32);
  if (n) {
    unsigned sl = (unsigned)(v & 0xffffffffu);
    unsigned cb = (unsigned)(excl >> 32);
    unsigned sb = (unsigned)(excl & 0xffffffffu);
    double Sb = (double)sb + (double)sl;
    double gb = 1.0 - (T - Sb) / (T + (double)(cb + n) - Sb);
    double ga = (cb == 0) ? 0.0
                          : 1.0 - (T - (double)sb) / (T + (double)cb - (double)sb);
    // log-uniform bin center: e = 2^((bin+0.5)/64 - 12)
    float e = exp2f(((float)bin + 0.5f) * 0.015625f - 12.0f);
    acc = (double)e * (gb - ga);
  }

  // block reduce acc (12 waves)
  #pragma unroll
  for (int off = 32; off > 0; off >>= 1) acc += __shfl_down(acc, off, 64);
  if (lane == 0) wred[wave] = acc;
  __syncthreads();
  if (tid == 0) {
    double ssum = 0.0;
    #pragma unroll
    for (int w = 0; w < 12; ++w) ssum += wred[w];
    atomicAdd(out, (float)(ssum * (1.0 / (double)NROWS)));
  }
}

extern "C" void kernel_launch(void* const* d_in, const int* in_sizes, int n_in,
                              void* d_out, int out_size, void* d_ws, size_t ws_size,
                              hipStream_t stream) {
  const float* x  = (const float*)d_in[0];   // (B, C, H, W) float32
  const int* tgt  = (const int*)d_in[1];     // (B, H, W) int32
  float* out      = (float*)d_out;
  unsigned* partial = (unsigned*)d_ws;       // 512*21*768*4 = 33 MB

  hipMemsetAsync(d_out, 0, sizeof(float), stream);
  k_fused<<<NB * CHUNKS, 1024, 0, stream>>>(x, tgt, partial);
  k_scan<<<NROWS, NBINS, 0, stream>>>(partial, out);
}